// Round 1
// baseline (503.693 us; speedup 1.0000x reference)
//
#include <hip/hip_runtime.h>
#include <hip/hip_bf16.h>
#include <cfloat>

// Problem constants (reference: B=4, L=4096, D=1024, H=16, Dh=64)
#define BB 4
#define LL 4096
#define DD 1024
#define HH 16
#define DHH 64
#define MM (BB * LL)          // 16384 rows
#define LN_EPS 1e-5f

typedef __hip_bfloat16 bf16;
typedef __attribute__((ext_vector_type(8))) short short8;
typedef __attribute__((ext_vector_type(4))) float float4_t;

struct bf16x4 { bf16 a, b, c, d; };

// ---------------------------------------------------------------------------
// f32 -> bf16 conversion (4 elems/thread, n must be multiple of 4)
// ---------------------------------------------------------------------------
__global__ __launch_bounds__(256) void cvt_f32_bf16(const float* __restrict__ in,
                                                    bf16* __restrict__ out, int n) {
    int i = (blockIdx.x * 256 + threadIdx.x) * 4;
    if (i >= n) return;
    float4 f = *(const float4*)(in + i);
    bf16x4 o;
    o.a = __float2bfloat16(f.x);
    o.b = __float2bfloat16(f.y);
    o.c = __float2bfloat16(f.z);
    o.d = __float2bfloat16(f.w);
    *(bf16x4*)(out + i) = o;
}

// ---------------------------------------------------------------------------
// async 16B global -> LDS
// ---------------------------------------------------------------------------
__device__ __forceinline__ void async16(const void* g, void* l) {
    __builtin_amdgcn_global_load_lds(
        (const __attribute__((address_space(1))) void*)g,
        (__attribute__((address_space(3))) void*)l,
        16, 0, 0);
}

// ---------------------------------------------------------------------------
// GEMM: C[M,N] = A[M,K] * B[N,K]^T   (both A and B row-major, K contiguous)
// bf16 inputs, f32 accumulate, OutT output. M,N multiples of 128, K mult of 32.
// 128x128 tile, 256 threads (4 waves, 2x2 of 64x64), 16x16x32 bf16 MFMA.
// ---------------------------------------------------------------------------
template <typename OutT>
__global__ __launch_bounds__(256) void gemm_bt(const bf16* __restrict__ A,
                                               const bf16* __restrict__ Bm,
                                               OutT* __restrict__ C,
                                               int M, int N, int K) {
    __shared__ bf16 sA[128 * 32];
    __shared__ bf16 sB[128 * 32];

    const int t    = threadIdx.x;
    const int lane = t & 63;
    const int wave = t >> 6;
    const int wm   = (wave >> 1) * 64;   // wave row offset in tile
    const int wn   = (wave & 1) * 64;    // wave col offset in tile

    const int bm = blockIdx.x;           // M/128
    const int bn = blockIdx.y;           // N/128

    // staging addresses: thread t covers 16B chunk t (rows 0..63) and t+256 (rows 64..127)
    const int srow = t >> 2;             // 0..63
    const int skc  = (t & 3) * 8;        // k element offset within 32
    const size_t arow0 = (size_t)(bm * 128 + srow) * K;
    const size_t brow0 = (size_t)(bn * 128 + srow) * K;

    const int mrow = wm + (lane & 15);
    const int nrow = wn + (lane & 15);
    const int koff = (lane >> 4) * 8;    // 0,8,16,24

    float4_t acc[4][4] = {};

    for (int k0 = 0; k0 < K; k0 += 32) {
        const bf16* ga = A + arow0 + k0 + skc;
        const bf16* gb = Bm + brow0 + k0 + skc;
        async16(ga,                sA + t * 8);
        async16(ga + (size_t)64*K, sA + (t + 256) * 8);
        async16(gb,                sB + t * 8);
        async16(gb + (size_t)64*K, sB + (t + 256) * 8);
        __syncthreads();   // compiler emits vmcnt(0)+lgkmcnt(0) drain before barrier

        short8 af[4], bfr[4];
#pragma unroll
        for (int mi = 0; mi < 4; ++mi)
            af[mi] = *(const short8*)(sA + (mrow + mi * 16) * 32 + koff);
#pragma unroll
        for (int ni = 0; ni < 4; ++ni)
            bfr[ni] = *(const short8*)(sB + (nrow + ni * 16) * 32 + koff);

#pragma unroll
        for (int mi = 0; mi < 4; ++mi)
#pragma unroll
            for (int ni = 0; ni < 4; ++ni)
                acc[mi][ni] = __builtin_amdgcn_mfma_f32_16x16x32_bf16(
                    af[mi], bfr[ni], acc[mi][ni], 0, 0, 0);
        __syncthreads();
    }

    // epilogue: D row = (lane>>4)*4 + reg, col = lane&15 within each 16x16 tile
    const int rbase = bm * 128 + wm + ((lane >> 4) << 2);
    const int cbase = bn * 128 + wn + (lane & 15);
#pragma unroll
    for (int mi = 0; mi < 4; ++mi) {
#pragma unroll
        for (int ni = 0; ni < 4; ++ni) {
#pragma unroll
            for (int r = 0; r < 4; ++r) {
                int row = rbase + mi * 16 + r;
                int col = cbase + ni * 16;
                C[(size_t)row * N + col] = (OutT)acc[mi][ni][r];
            }
        }
    }
}

// ---------------------------------------------------------------------------
// Retention scan: s_t = lam*s_{t-1} + v_t along L, then ret = q * s.
// Chunked with warm-up (lam^768 < 4e-6 -> exact within tolerance).
// grid: (chunks=8, H, B), block: 64 (one dh per lane). ret may alias q.
// ---------------------------------------------------------------------------
#define SCAN_CHUNK 512
#define SCAN_WARM  768

__global__ __launch_bounds__(64) void retention_scan(const bf16* __restrict__ q,
                                                     const bf16* __restrict__ v,
                                                     const float* __restrict__ beta,
                                                     bf16* __restrict__ ret) {
    const int chunk = blockIdx.x;
    const int h     = blockIdx.y;
    const int b     = blockIdx.z;
    const int dh    = threadIdx.x;

    float lam = 1.0f - exp2f(-beta[h]);
    lam = fminf(fmaxf(lam, 1.1754944e-38f), 1.0f - 1e-9f);

    const int t0 = chunk * SCAN_CHUNK;
    const int tw = (t0 - SCAN_WARM > 0) ? (t0 - SCAN_WARM) : 0;

    const size_t base = (size_t)b * LL * DD + (size_t)h * DHH + dh;

    float s = 0.0f;
#pragma unroll 4
    for (int t = tw; t < t0; ++t) {
        float vv = __bfloat162float(v[base + (size_t)t * DD]);
        s = lam * s + vv;
    }
#pragma unroll 4
    for (int t = t0; t < t0 + SCAN_CHUNK; ++t) {
        size_t idx = base + (size_t)t * DD;
        float vv = __bfloat162float(v[idx]);
        s = lam * s + vv;
        float qq = __bfloat162float(q[idx]);
        ret[idx] = __float2bfloat16(qq * s);
    }
}

// ---------------------------------------------------------------------------
// Fused LayerNorm(ret) * SiLU(gpre) -> z (bf16). One block per row of 1024.
// ---------------------------------------------------------------------------
__global__ __launch_bounds__(256) void ln_gate(const bf16* __restrict__ ret,
                                               const bf16* __restrict__ gp,
                                               const float* __restrict__ gamma,
                                               const float* __restrict__ betaln,
                                               bf16* __restrict__ z) {
    const int row  = blockIdx.x;
    const int tid  = threadIdx.x;
    const int lane = tid & 63;
    const int wave = tid >> 6;
    const size_t base = (size_t)row * DD + tid * 4;

    bf16x4 rv = *(const bf16x4*)(ret + base);
    float x0 = __bfloat162float(rv.a);
    float x1 = __bfloat162float(rv.b);
    float x2 = __bfloat162float(rv.c);
    float x3 = __bfloat162float(rv.d);

    float s  = x0 + x1 + x2 + x3;
    float s2 = x0 * x0 + x1 * x1 + x2 * x2 + x3 * x3;
#pragma unroll
    for (int off = 32; off >= 1; off >>= 1) {
        s  += __shfl_xor(s, off, 64);
        s2 += __shfl_xor(s2, off, 64);
    }
    __shared__ float red[8];
    if (lane == 0) { red[wave] = s; red[wave + 4] = s2; }
    __syncthreads();
    s  = red[0] + red[1] + red[2] + red[3];
    s2 = red[4] + red[5] + red[6] + red[7];

    const float mu   = s * (1.0f / DD);
    const float var  = s2 * (1.0f / DD) - mu * mu;
    const float rstd = rsqrtf(var + LN_EPS);

    bf16x4 gv = *(const bf16x4*)(gp + base);
    float4 gm = *(const float4*)(gamma + tid * 4);
    float4 bt = *(const float4*)(betaln + tid * 4);

    float xs[4] = {x0, x1, x2, x3};
    float gs[4] = {__bfloat162float(gv.a), __bfloat162float(gv.b),
                   __bfloat162float(gv.c), __bfloat162float(gv.d)};
    float gmm[4] = {gm.x, gm.y, gm.z, gm.w};
    float btt[4] = {bt.x, bt.y, bt.z, bt.w};

    bf16x4 o;
    bf16* op = &o.a;
#pragma unroll
    for (int j = 0; j < 4; ++j) {
        float y  = (xs[j] - mu) * rstd * gmm[j] + btt[j];
        float g  = gs[j];
        float sg = g / (1.0f + expf(-g));
        op[j] = __float2bfloat16(y * sg);
    }
    *(bf16x4*)(z + base) = o;
}

// ---------------------------------------------------------------------------
// launch
// ---------------------------------------------------------------------------
extern "C" void kernel_launch(void* const* d_in, const int* in_sizes, int n_in,
                              void* d_out, int out_size, void* d_ws, size_t ws_size,
                              hipStream_t stream) {
    const float* x     = (const float*)d_in[0];
    const float* Wq    = (const float*)d_in[1];
    const float* Wv    = (const float*)d_in[2];
    const float* Wo    = (const float*)d_in[3];
    const float* Wg    = (const float*)d_in[4];
    const float* beta  = (const float*)d_in[5];
    const float* ln_g  = (const float*)d_in[6];
    const float* ln_b  = (const float*)d_in[7];
    float* out = (float*)d_out;

    char* ws = (char*)d_ws;
    // workspace layout (bytes):
    //   xb  : 32MB  @ 0          (bf16 x, later reused as z)
    //   wqb : 2MB   @ 32MB
    //   wvb : 2MB   @ 34MB
    //   wgb : 2MB   @ 36MB
    //   wob : 2MB   @ 38MB
    //   qb  : 32MB  @ 40MB       (ret written in place)
    //   vb  : 32MB  @ 72MB
    //   gb  : 32MB  @ 104MB      -> total 136MB
    bf16* xb  = (bf16*)ws;
    bf16* wqb = (bf16*)(ws + (size_t)32 * 1024 * 1024);
    bf16* wvb = wqb + 1048576;
    bf16* wgb = wvb + 1048576;
    bf16* wob = wgb + 1048576;
    bf16* qb  = (bf16*)(ws + (size_t)40 * 1024 * 1024);
    bf16* vb  = qb + (size_t)MM * DD;
    bf16* gb  = vb + (size_t)MM * DD;
    bf16* zb  = xb;   // alias: xb dead after the three input GEMMs

    // convert inputs to bf16
    cvt_f32_bf16<<<dim3((MM * DD) / 1024), dim3(256), 0, stream>>>(x, xb, MM * DD);
    cvt_f32_bf16<<<dim3((DD * DD) / 1024), dim3(256), 0, stream>>>(Wq, wqb, DD * DD);
    cvt_f32_bf16<<<dim3((DD * DD) / 1024), dim3(256), 0, stream>>>(Wv, wvb, DD * DD);
    cvt_f32_bf16<<<dim3((DD * DD) / 1024), dim3(256), 0, stream>>>(Wg, wgb, DD * DD);
    cvt_f32_bf16<<<dim3((DD * DD) / 1024), dim3(256), 0, stream>>>(Wo, wob, DD * DD);

    dim3 ggrid(MM / 128, DD / 128);
    gemm_bt<bf16><<<ggrid, dim3(256), 0, stream>>>(xb, wqb, qb, MM, DD, DD);
    gemm_bt<bf16><<<ggrid, dim3(256), 0, stream>>>(xb, wvb, vb, MM, DD, DD);
    gemm_bt<bf16><<<ggrid, dim3(256), 0, stream>>>(xb, wgb, gb, MM, DD, DD);

    retention_scan<<<dim3(LL / SCAN_CHUNK, HH, BB), dim3(64), 0, stream>>>(qb, vb, beta, qb);

    ln_gate<<<dim3(MM), dim3(256), 0, stream>>>(qb, gb, ln_g, ln_b, zb);

    gemm_bt<float><<<ggrid, dim3(256), 0, stream>>>(zb, wob, out, MM, DD, DD);
}

// Round 2
// 424.500 us; speedup vs baseline: 1.1866x; 1.1866x over previous
//
#include <hip/hip_runtime.h>
#include <hip/hip_bf16.h>
#include <cfloat>

// Problem constants (reference: B=4, L=4096, D=1024, H=16, Dh=64)
#define BB 4
#define LL 4096
#define DD 1024
#define HH 16
#define DHH 64
#define MM (BB * LL)          // 16384 rows
#define LN_EPS 1e-5f
#define LDQVG 3072            // fused q|v|g row stride

typedef __hip_bfloat16 bf16;
typedef __attribute__((ext_vector_type(8))) short short8;
typedef __attribute__((ext_vector_type(4))) float float4_t;

struct bf16x4 { bf16 a, b, c, d; };
struct alignas(16) bf8 { bf16 e[8]; };

__device__ __forceinline__ float b2f(bf16 u) {
    union { unsigned int i; float f; } c;
    c.i = ((unsigned int)__bfloat16_as_ushort(u)) << 16;
    return c.f;
}

// ---------------------------------------------------------------------------
// f32 -> bf16 conversion (4 elems/thread, n must be multiple of 1024)
// ---------------------------------------------------------------------------
__global__ __launch_bounds__(256) void cvt_f32_bf16(const float* __restrict__ in,
                                                    bf16* __restrict__ out, int n) {
    int i = (blockIdx.x * 256 + threadIdx.x) * 4;
    if (i >= n) return;
    float4 f = *(const float4*)(in + i);
    bf16x4 o;
    o.a = __float2bfloat16(f.x);
    o.b = __float2bfloat16(f.y);
    o.c = __float2bfloat16(f.z);
    o.d = __float2bfloat16(f.w);
    *(bf16x4*)(out + i) = o;
}

// 4 weight matrices (1M f32 each) -> contiguous bf16 (wq|wv|wg|wo). grid 4096.
__global__ __launch_bounds__(256) void cvt4_weights(const float* __restrict__ w0,
                                                    const float* __restrict__ w1,
                                                    const float* __restrict__ w2,
                                                    const float* __restrict__ w3,
                                                    bf16* __restrict__ o) {
    int which = blockIdx.x >> 10;
    int i = ((blockIdx.x & 1023) * 256 + threadIdx.x) * 4;
    const float* w = (which == 0) ? w0 : (which == 1) ? w1 : (which == 2) ? w2 : w3;
    float4 f = *(const float4*)(w + i);
    bf16x4 r;
    r.a = __float2bfloat16(f.x);
    r.b = __float2bfloat16(f.y);
    r.c = __float2bfloat16(f.z);
    r.d = __float2bfloat16(f.w);
    *(bf16x4*)(o + (size_t)which * 1048576 + i) = r;
}

// ---------------------------------------------------------------------------
// async 16B global -> LDS
// ---------------------------------------------------------------------------
__device__ __forceinline__ void async16(const void* g, void* l) {
    __builtin_amdgcn_global_load_lds(
        (const __attribute__((address_space(1))) void*)g,
        (__attribute__((address_space(3))) void*)l,
        16, 0, 0);
}

// ---------------------------------------------------------------------------
// GEMM: C[M,N] = A[M,K] * B[N,K]^T  (row-major, K contiguous), ldc row stride.
// 128x128 tile, 256 threads (2x2 waves of 64x64), 16x16x32 bf16 MFMA.
// ---------------------------------------------------------------------------
template <typename OutT>
__global__ __launch_bounds__(256) void gemm_bt(const bf16* __restrict__ A,
                                               const bf16* __restrict__ Bm,
                                               OutT* __restrict__ C,
                                               int M, int N, int K, int ldc) {
    __shared__ bf16 sA[128 * 32];
    __shared__ bf16 sB[128 * 32];

    const int t    = threadIdx.x;
    const int lane = t & 63;
    const int wave = t >> 6;
    const int wm   = (wave >> 1) * 64;
    const int wn   = (wave & 1) * 64;

    const int bm = blockIdx.x;
    const int bn = blockIdx.y;

    const int srow = t >> 2;
    const int skc  = (t & 3) * 8;
    const size_t arow0 = (size_t)(bm * 128 + srow) * K;
    const size_t brow0 = (size_t)(bn * 128 + srow) * K;

    const int mrow = wm + (lane & 15);
    const int nrow = wn + (lane & 15);
    const int koff = (lane >> 4) * 8;

    float4_t acc[4][4] = {};

    for (int k0 = 0; k0 < K; k0 += 32) {
        const bf16* ga = A + arow0 + k0 + skc;
        const bf16* gb = Bm + brow0 + k0 + skc;
        async16(ga,                sA + t * 8);
        async16(ga + (size_t)64*K, sA + (t + 256) * 8);
        async16(gb,                sB + t * 8);
        async16(gb + (size_t)64*K, sB + (t + 256) * 8);
        __syncthreads();

        short8 af[4], bfr[4];
#pragma unroll
        for (int mi = 0; mi < 4; ++mi)
            af[mi] = *(const short8*)(sA + (mrow + mi * 16) * 32 + koff);
#pragma unroll
        for (int ni = 0; ni < 4; ++ni)
            bfr[ni] = *(const short8*)(sB + (nrow + ni * 16) * 32 + koff);

#pragma unroll
        for (int mi = 0; mi < 4; ++mi)
#pragma unroll
            for (int ni = 0; ni < 4; ++ni)
                acc[mi][ni] = __builtin_amdgcn_mfma_f32_16x16x32_bf16(
                    af[mi], bfr[ni], acc[mi][ni], 0, 0, 0);
        __syncthreads();
    }

    const int rbase = bm * 128 + wm + ((lane >> 4) << 2);
    const int cbase = bn * 128 + wn + (lane & 15);
#pragma unroll
    for (int mi = 0; mi < 4; ++mi) {
#pragma unroll
        for (int ni = 0; ni < 4; ++ni) {
#pragma unroll
            for (int r = 0; r < 4; ++r) {
                int row = rbase + mi * 16 + r;
                int col = cbase + ni * 16;
                C[(size_t)row * ldc + col] = (OutT)acc[mi][ni][r];
            }
        }
    }
}

// ---------------------------------------------------------------------------
// Retention scan over fused qvg layout (row stride 3072: q|v|g).
// Each lane owns 8 consecutive dh (16B vector loads), 8 scalar recurrences.
// Chunked with warm-up: lam^512 <= 2.2e-4 -> truncation error ~1e-3, ok.
// grid: (L/SC_CHUNK, 2 halves of D, B), block 64. ret written in place over q.
// ---------------------------------------------------------------------------
#define SC_CHUNK 64
#define SC_WARM  512

__global__ __launch_bounds__(64) void retention_scan(bf16* __restrict__ qvg,
                                                     const float* __restrict__ beta) {
    const int chunk = blockIdx.x;
    const int half  = blockIdx.y;
    const int b     = blockIdx.z;
    const int tid   = threadIdx.x;            // 0..63
    const int dh0   = half * 512 + tid * 8;   // global feature index (0..1023)
    const int head  = dh0 >> 6;

    float lam = 1.0f - exp2f(-beta[head]);
    lam = fminf(fmaxf(lam, 1.1754944e-38f), 1.0f - 1e-9f);

    const int t0 = chunk * SC_CHUNK;
    const int tw = (t0 - SC_WARM > 0) ? (t0 - SC_WARM) : 0;

    const size_t base = ((size_t)b * LL) * LDQVG + dh0;
    const bf16* vp = qvg + 1024;

    float s[8] = {0.f, 0.f, 0.f, 0.f, 0.f, 0.f, 0.f, 0.f};

#pragma unroll 4
    for (int t = tw; t < t0; ++t) {
        bf8 vv = *(const bf8*)(vp + base + (size_t)t * LDQVG);
#pragma unroll
        for (int j = 0; j < 8; ++j)
            s[j] = fmaf(s[j], lam, b2f(vv.e[j]));
    }

#pragma unroll 2
    for (int t = t0; t < t0 + SC_CHUNK; ++t) {
        const size_t off = base + (size_t)t * LDQVG;
        bf8 vv = *(const bf8*)(vp + off);
        bf8 qq = *(const bf8*)(qvg + off);
        bf8 o;
#pragma unroll
        for (int j = 0; j < 8; ++j) {
            s[j] = fmaf(s[j], lam, b2f(vv.e[j]));
            o.e[j] = __float2bfloat16(b2f(qq.e[j]) * s[j]);
        }
        *(bf8*)(qvg + off) = o;
    }
}

// ---------------------------------------------------------------------------
// Fused LayerNorm(ret) * SiLU(gpre) -> z (bf16, contiguous [M,1024]).
// ret at qvg[row*3072 + 0..1023], g at qvg[row*3072 + 2048..3071].
// ---------------------------------------------------------------------------
__global__ __launch_bounds__(256) void ln_gate(const bf16* __restrict__ qvg,
                                               const float* __restrict__ gamma,
                                               const float* __restrict__ betaln,
                                               bf16* __restrict__ z) {
    const int row  = blockIdx.x;
    const int tid  = threadIdx.x;
    const int lane = tid & 63;
    const int wave = tid >> 6;
    const size_t rbase = (size_t)row * LDQVG + tid * 4;

    bf16x4 rv = *(const bf16x4*)(qvg + rbase);
    float x0 = b2f(rv.a), x1 = b2f(rv.b), x2 = b2f(rv.c), x3 = b2f(rv.d);

    float s  = x0 + x1 + x2 + x3;
    float s2 = x0 * x0 + x1 * x1 + x2 * x2 + x3 * x3;
#pragma unroll
    for (int off = 32; off >= 1; off >>= 1) {
        s  += __shfl_xor(s, off, 64);
        s2 += __shfl_xor(s2, off, 64);
    }
    __shared__ float red[8];
    if (lane == 0) { red[wave] = s; red[wave + 4] = s2; }
    __syncthreads();
    s  = red[0] + red[1] + red[2] + red[3];
    s2 = red[4] + red[5] + red[6] + red[7];

    const float mu   = s * (1.0f / DD);
    const float var  = s2 * (1.0f / DD) - mu * mu;
    const float rstd = rsqrtf(var + LN_EPS);

    bf16x4 gv = *(const bf16x4*)(qvg + rbase + 2048);
    float4 gm = *(const float4*)(gamma + tid * 4);
    float4 bt = *(const float4*)(betaln + tid * 4);

    float xs[4]  = {x0, x1, x2, x3};
    float gs[4]  = {b2f(gv.a), b2f(gv.b), b2f(gv.c), b2f(gv.d)};
    float gmm[4] = {gm.x, gm.y, gm.z, gm.w};
    float btt[4] = {bt.x, bt.y, bt.z, bt.w};

    bf16x4 o;
    bf16* op = &o.a;
#pragma unroll
    for (int j = 0; j < 4; ++j) {
        float y  = (xs[j] - mu) * rstd * gmm[j] + btt[j];
        float g  = gs[j];
        float sg = g / (1.0f + expf(-g));
        op[j] = __float2bfloat16(y * sg);
    }
    *(bf16x4*)(z + (size_t)row * DD + tid * 4) = o;
}

// ---------------------------------------------------------------------------
// launch
// ---------------------------------------------------------------------------
extern "C" void kernel_launch(void* const* d_in, const int* in_sizes, int n_in,
                              void* d_out, int out_size, void* d_ws, size_t ws_size,
                              hipStream_t stream) {
    const float* x     = (const float*)d_in[0];
    const float* Wq    = (const float*)d_in[1];
    const float* Wv    = (const float*)d_in[2];
    const float* Wo    = (const float*)d_in[3];
    const float* Wg    = (const float*)d_in[4];
    const float* beta  = (const float*)d_in[5];
    const float* ln_g  = (const float*)d_in[6];
    const float* ln_b  = (const float*)d_in[7];
    float* out = (float*)d_out;

    char* ws = (char*)d_ws;
    // workspace layout (bytes):
    //   xb  : 32MB @ 0        (bf16 x; reused as z after QVG GEMM)
    //   wqb : 2MB  @ 32MB     | wq|wv|wg contiguous -> fused N=3072 GEMM B
    //   wvb : 2MB  @ 34MB
    //   wgb : 2MB  @ 36MB
    //   wob : 2MB  @ 38MB
    //   qvg : 96MB @ 40MB     ([M,3072] = q|v|g per row)  -> total 136MB
    bf16* xb  = (bf16*)ws;
    bf16* wqb = (bf16*)(ws + (size_t)32 * 1024 * 1024);
    bf16* wob = wqb + 3 * 1048576;
    bf16* qvg = (bf16*)(ws + (size_t)40 * 1024 * 1024);
    bf16* zb  = xb;   // alias: xb dead after the QVG GEMM

    cvt_f32_bf16<<<dim3((MM * DD) / 1024), dim3(256), 0, stream>>>(x, xb, MM * DD);
    // weight order in buffer: Wq, Wv, Wg (fused B), then Wo
    cvt4_weights<<<dim3(4096), dim3(256), 0, stream>>>(Wq, Wv, Wg, Wo, wqb);

    // fused QVG GEMM: [M,1024] x [3072,1024]^T -> [M,3072]
    gemm_bt<bf16><<<dim3(MM / 128, LDQVG / 128), dim3(256), 0, stream>>>(
        xb, wqb, qvg, MM, LDQVG, DD, LDQVG);

    retention_scan<<<dim3(LL / SC_CHUNK, 2, BB), dim3(64), 0, stream>>>(qvg, beta);

    ln_gate<<<dim3(MM), dim3(256), 0, stream>>>(qvg, ln_g, ln_b, zb);

    gemm_bt<float><<<dim3(MM / 128, DD / 128), dim3(256), 0, stream>>>(
        zb, wob, out, MM, DD, DD, DD);
}

// Round 3
// 391.522 us; speedup vs baseline: 1.2865x; 1.0842x over previous
//
#include <hip/hip_runtime.h>
#include <hip/hip_bf16.h>
#include <cfloat>

// Problem constants (reference: B=4, L=4096, D=1024, H=16, Dh=64)
#define BB 4
#define LL 4096
#define DD 1024
#define HH 16
#define DHH 64
#define MM (BB * LL)          // 16384 rows
#define LN_EPS 1e-5f
#define LDQVG 3072            // fused q|v|g row stride
#define SCC 16                // scan chunk length
#define NCHUNK (LL / SCC)     // 256 chunks per batch

typedef __hip_bfloat16 bf16;
typedef __attribute__((ext_vector_type(8))) short short8;
typedef __attribute__((ext_vector_type(4))) float float4_t;

struct bf16x4 { bf16 a, b, c, d; };
struct alignas(16) bf8 { bf16 e[8]; };

__device__ __forceinline__ float b2f(bf16 u) {
    union { unsigned int i; float f; } c;
    c.i = ((unsigned int)__bfloat16_as_ushort(u)) << 16;
    return c.f;
}

__device__ __forceinline__ float lam_of(const float* beta, int head) {
    float lam = 1.0f - exp2f(-beta[head]);
    return fminf(fmaxf(lam, 1.1754944e-38f), 1.0f - 1e-9f);
}

// ---------------------------------------------------------------------------
// f32 -> bf16 conversion (4 elems/thread, n must be multiple of 1024)
// ---------------------------------------------------------------------------
__global__ __launch_bounds__(256) void cvt_f32_bf16(const float* __restrict__ in,
                                                    bf16* __restrict__ out, int n) {
    int i = (blockIdx.x * 256 + threadIdx.x) * 4;
    if (i >= n) return;
    float4 f = *(const float4*)(in + i);
    bf16x4 o;
    o.a = __float2bfloat16(f.x);
    o.b = __float2bfloat16(f.y);
    o.c = __float2bfloat16(f.z);
    o.d = __float2bfloat16(f.w);
    *(bf16x4*)(out + i) = o;
}

// 4 weight matrices (1M f32 each) -> contiguous bf16 (wq|wv|wg|wo). grid 4096.
__global__ __launch_bounds__(256) void cvt4_weights(const float* __restrict__ w0,
                                                    const float* __restrict__ w1,
                                                    const float* __restrict__ w2,
                                                    const float* __restrict__ w3,
                                                    bf16* __restrict__ o) {
    int which = blockIdx.x >> 10;
    int i = ((blockIdx.x & 1023) * 256 + threadIdx.x) * 4;
    const float* w = (which == 0) ? w0 : (which == 1) ? w1 : (which == 2) ? w2 : w3;
    float4 f = *(const float4*)(w + i);
    bf16x4 r;
    r.a = __float2bfloat16(f.x);
    r.b = __float2bfloat16(f.y);
    r.c = __float2bfloat16(f.z);
    r.d = __float2bfloat16(f.w);
    *(bf16x4*)(o + (size_t)which * 1048576 + i) = r;
}

// ---------------------------------------------------------------------------
// async 16B global -> LDS
// ---------------------------------------------------------------------------
__device__ __forceinline__ void async16(const void* g, void* l) {
    __builtin_amdgcn_global_load_lds(
        (const __attribute__((address_space(1))) void*)g,
        (__attribute__((address_space(3))) void*)l,
        16, 0, 0);
}

// ---------------------------------------------------------------------------
// GEMM: C[M,N] = A[M,K] * B[N,K]^T  (row-major, K contiguous), ldc row stride.
// 128x128 tile, 256 threads (2x2 waves of 64x64), 16x16x32 bf16 MFMA.
// ---------------------------------------------------------------------------
template <typename OutT>
__global__ __launch_bounds__(256) void gemm_bt(const bf16* __restrict__ A,
                                               const bf16* __restrict__ Bm,
                                               OutT* __restrict__ C,
                                               int M, int N, int K, int ldc) {
    __shared__ bf16 sA[128 * 32];
    __shared__ bf16 sB[128 * 32];

    const int t    = threadIdx.x;
    const int lane = t & 63;
    const int wave = t >> 6;
    const int wm   = (wave >> 1) * 64;
    const int wn   = (wave & 1) * 64;

    const int bm = blockIdx.x;
    const int bn = blockIdx.y;

    const int srow = t >> 2;
    const int skc  = (t & 3) * 8;
    const size_t arow0 = (size_t)(bm * 128 + srow) * K;
    const size_t brow0 = (size_t)(bn * 128 + srow) * K;

    const int mrow = wm + (lane & 15);
    const int nrow = wn + (lane & 15);
    const int koff = (lane >> 4) * 8;

    float4_t acc[4][4] = {};

    for (int k0 = 0; k0 < K; k0 += 32) {
        const bf16* ga = A + arow0 + k0 + skc;
        const bf16* gb = Bm + brow0 + k0 + skc;
        async16(ga,                sA + t * 8);
        async16(ga + (size_t)64*K, sA + (t + 256) * 8);
        async16(gb,                sB + t * 8);
        async16(gb + (size_t)64*K, sB + (t + 256) * 8);
        __syncthreads();

        short8 af[4], bfr[4];
#pragma unroll
        for (int mi = 0; mi < 4; ++mi)
            af[mi] = *(const short8*)(sA + (mrow + mi * 16) * 32 + koff);
#pragma unroll
        for (int ni = 0; ni < 4; ++ni)
            bfr[ni] = *(const short8*)(sB + (nrow + ni * 16) * 32 + koff);

#pragma unroll
        for (int mi = 0; mi < 4; ++mi)
#pragma unroll
            for (int ni = 0; ni < 4; ++ni)
                acc[mi][ni] = __builtin_amdgcn_mfma_f32_16x16x32_bf16(
                    af[mi], bfr[ni], acc[mi][ni], 0, 0, 0);
        __syncthreads();
    }

    const int rbase = bm * 128 + wm + ((lane >> 4) << 2);
    const int cbase = bn * 128 + wn + (lane & 15);
#pragma unroll
    for (int mi = 0; mi < 4; ++mi) {
#pragma unroll
        for (int ni = 0; ni < 4; ++ni) {
#pragma unroll
            for (int r = 0; r < 4; ++r) {
                int row = rbase + mi * 16 + r;
                int col = cbase + ni * 16;
                C[(size_t)row * ldc + col] = (OutT)acc[mi][ni][r];
            }
        }
    }
}

// ---------------------------------------------------------------------------
// Exact two-phase retention scan over fused qvg layout (row stride 3072).
// Phase A: per-chunk local scan (zero init) -> chunk sums S[b][c][f] (f32).
// Phase B: carry scan across chunks: T[c] = S[c-1] + lam^SCC * T[c-1], T[0]=0.
// Phase C: re-scan chunk from carry T, write ret = q*s in place over q.
// Exact (no warm-up truncation). v is read twice total.
// ---------------------------------------------------------------------------
__global__ __launch_bounds__(64) void scan_chunksum(const bf16* __restrict__ qvg,
                                                    const float* __restrict__ beta,
                                                    float* __restrict__ S) {
    const int c    = blockIdx.x;            // 0..NCHUNK-1
    const int half = blockIdx.y;            // 0..1
    const int b    = blockIdx.z;
    const int tid  = threadIdx.x;           // 0..63
    const int dh0  = half * 512 + tid * 8;  // feature index
    const float lam = lam_of(beta, dh0 >> 6);

    const bf16* vp = qvg + 1024 + ((size_t)(b * LL + c * SCC)) * LDQVG + dh0;

    float s[8] = {};
#pragma unroll
    for (int t = 0; t < SCC; ++t) {
        bf8 vv = *(const bf8*)(vp + (size_t)t * LDQVG);
#pragma unroll
        for (int j = 0; j < 8; ++j)
            s[j] = fmaf(s[j], lam, b2f(vv.e[j]));
    }

    float* sp = S + ((size_t)(b * NCHUNK + c)) * DD + dh0;
    float4 lo = {s[0], s[1], s[2], s[3]};
    float4 hi = {s[4], s[5], s[6], s[7]};
    *(float4*)(sp)     = lo;
    *(float4*)(sp + 4) = hi;
}

// grid 64 x block 64 = 4096 threads; thread owns one (b,f) column of chunks.
__global__ __launch_bounds__(64) void scan_carry(const float* __restrict__ S,
                                                 float* __restrict__ T,
                                                 const float* __restrict__ beta) {
    const int gid = blockIdx.x * 64 + threadIdx.x;  // 0..4095
    const int b = gid >> 10;
    const int f = gid & 1023;
    const float lam  = lam_of(beta, f >> 6);
    const float lamC = powf(lam, (float)SCC);

    const size_t base = (size_t)b * NCHUNK * DD + f;
    float t = 0.0f;
    for (int c = 0; c < NCHUNK; ++c) {
        float s = S[base + (size_t)c * DD];
        T[base + (size_t)c * DD] = t;
        t = fmaf(t, lamC, s);
    }
}

__global__ __launch_bounds__(64) void scan_apply(bf16* __restrict__ qvg,
                                                 const float* __restrict__ beta,
                                                 const float* __restrict__ T) {
    const int c    = blockIdx.x;
    const int half = blockIdx.y;
    const int b    = blockIdx.z;
    const int tid  = threadIdx.x;
    const int dh0  = half * 512 + tid * 8;
    const float lam = lam_of(beta, dh0 >> 6);

    const float* tp = T + ((size_t)(b * NCHUNK + c)) * DD + dh0;
    float4 lo = *(const float4*)(tp);
    float4 hi = *(const float4*)(tp + 4);
    float s[8] = {lo.x, lo.y, lo.z, lo.w, hi.x, hi.y, hi.z, hi.w};

    bf16* qp = qvg + ((size_t)(b * LL + c * SCC)) * LDQVG + dh0;

#pragma unroll
    for (int t = 0; t < SCC; ++t) {
        const size_t off = (size_t)t * LDQVG;
        bf8 vv = *(const bf8*)(qp + 1024 + off);
        bf8 qq = *(const bf8*)(qp + off);
        bf8 o;
#pragma unroll
        for (int j = 0; j < 8; ++j) {
            s[j] = fmaf(s[j], lam, b2f(vv.e[j]));
            o.e[j] = __float2bfloat16(b2f(qq.e[j]) * s[j]);
        }
        *(bf8*)(qp + off) = o;
    }
}

// ---------------------------------------------------------------------------
// Fused LayerNorm(ret) * SiLU(gpre) -> z (bf16, contiguous [M,1024]).
// ret at qvg[row*3072 + 0..1023], g at qvg[row*3072 + 2048..3071].
// ---------------------------------------------------------------------------
__global__ __launch_bounds__(256) void ln_gate(const bf16* __restrict__ qvg,
                                               const float* __restrict__ gamma,
                                               const float* __restrict__ betaln,
                                               bf16* __restrict__ z) {
    const int row  = blockIdx.x;
    const int tid  = threadIdx.x;
    const int lane = tid & 63;
    const int wave = tid >> 6;
    const size_t rbase = (size_t)row * LDQVG + tid * 4;

    bf16x4 rv = *(const bf16x4*)(qvg + rbase);
    float x0 = b2f(rv.a), x1 = b2f(rv.b), x2 = b2f(rv.c), x3 = b2f(rv.d);

    float s  = x0 + x1 + x2 + x3;
    float s2 = x0 * x0 + x1 * x1 + x2 * x2 + x3 * x3;
#pragma unroll
    for (int off = 32; off >= 1; off >>= 1) {
        s  += __shfl_xor(s, off, 64);
        s2 += __shfl_xor(s2, off, 64);
    }
    __shared__ float red[8];
    if (lane == 0) { red[wave] = s; red[wave + 4] = s2; }
    __syncthreads();
    s  = red[0] + red[1] + red[2] + red[3];
    s2 = red[4] + red[5] + red[6] + red[7];

    const float mu   = s * (1.0f / DD);
    const float var  = s2 * (1.0f / DD) - mu * mu;
    const float rstd = rsqrtf(var + LN_EPS);

    bf16x4 gv = *(const bf16x4*)(qvg + rbase + 2048);
    float4 gm = *(const float4*)(gamma + tid * 4);
    float4 bt = *(const float4*)(betaln + tid * 4);

    float xs[4]  = {x0, x1, x2, x3};
    float gs[4]  = {b2f(gv.a), b2f(gv.b), b2f(gv.c), b2f(gv.d)};
    float gmm[4] = {gm.x, gm.y, gm.z, gm.w};
    float btt[4] = {bt.x, bt.y, bt.z, bt.w};

    bf16x4 o;
    bf16* op = &o.a;
#pragma unroll
    for (int j = 0; j < 4; ++j) {
        float y  = (xs[j] - mu) * rstd * gmm[j] + btt[j];
        float g  = gs[j];
        float sg = g / (1.0f + expf(-g));
        op[j] = __float2bfloat16(y * sg);
    }
    *(bf16x4*)(z + (size_t)row * DD + tid * 4) = o;
}

// ---------------------------------------------------------------------------
// launch
// ---------------------------------------------------------------------------
extern "C" void kernel_launch(void* const* d_in, const int* in_sizes, int n_in,
                              void* d_out, int out_size, void* d_ws, size_t ws_size,
                              hipStream_t stream) {
    const float* x     = (const float*)d_in[0];
    const float* Wq    = (const float*)d_in[1];
    const float* Wv    = (const float*)d_in[2];
    const float* Wo    = (const float*)d_in[3];
    const float* Wg    = (const float*)d_in[4];
    const float* beta  = (const float*)d_in[5];
    const float* ln_g  = (const float*)d_in[6];
    const float* ln_b  = (const float*)d_in[7];
    float* out = (float*)d_out;

    char* ws = (char*)d_ws;
    // workspace layout (bytes):
    //   xb  : 32MB @ 0      bf16 x for the QVG GEMM; dead afterwards. The same
    //                       region is then reused: S (4MB @0), T (4MB @4MB)
    //                       during the scan, then z (32MB @0) from ln_gate on.
    //   wqb : 6MB  @ 32MB   wq|wv|wg contiguous (fused N=3072 GEMM B)
    //   wob : 2MB  @ 38MB
    //   qvg : 96MB @ 40MB   [M,3072] = q|v|g per row      -> total 136MB
    bf16*  xb  = (bf16*)ws;
    float* Sbuf = (float*)ws;                                  // 4 MB (alias xb)
    float* Tbuf = (float*)(ws + (size_t)4 * 1024 * 1024);      // 4 MB (alias xb)
    bf16*  wqb = (bf16*)(ws + (size_t)32 * 1024 * 1024);
    bf16*  wob = wqb + 3 * 1048576;
    bf16*  qvg = (bf16*)(ws + (size_t)40 * 1024 * 1024);
    bf16*  zb  = xb;   // alias: xb/S/T dead by ln_gate

    cvt_f32_bf16<<<dim3((MM * DD) / 1024), dim3(256), 0, stream>>>(x, xb, MM * DD);
    // weight order in buffer: Wq, Wv, Wg (fused B), then Wo
    cvt4_weights<<<dim3(4096), dim3(256), 0, stream>>>(Wq, Wv, Wg, Wo, wqb);

    // fused QVG GEMM: [M,1024] x [3072,1024]^T -> [M,3072]
    gemm_bt<bf16><<<dim3(MM / 128, LDQVG / 128), dim3(256), 0, stream>>>(
        xb, wqb, qvg, MM, LDQVG, DD, LDQVG);

    // exact two-phase retention scan
    scan_chunksum<<<dim3(NCHUNK, 2, BB), dim3(64), 0, stream>>>(qvg, beta, Sbuf);
    scan_carry<<<dim3(64), dim3(64), 0, stream>>>(Sbuf, Tbuf, beta);
    scan_apply<<<dim3(NCHUNK, 2, BB), dim3(64), 0, stream>>>(qvg, beta, Tbuf);

    ln_gate<<<dim3(MM), dim3(256), 0, stream>>>(qvg, ln_g, ln_b, zb);

    gemm_bt<float><<<dim3(MM / 128, DD / 128), dim3(256), 0, stream>>>(
        zb, wob, out, MM, DD, DD, DD);
}

// Round 5
// 378.043 us; speedup vs baseline: 1.3324x; 1.0357x over previous
//
#include <hip/hip_runtime.h>
#include <hip/hip_bf16.h>
#include <cfloat>

// Problem constants (reference: B=4, L=4096, D=1024, H=16, Dh=64)
#define BB 4
#define LL 4096
#define DD 1024
#define HH 16
#define DHH 64
#define MM (BB * LL)          // 16384 rows
#define LN_EPS 1e-5f
#define LDQVG 3072            // fused q|v|g row stride
#define SCC 16                // scan chunk length
#define NCHUNK (LL / SCC)     // 256 chunks per batch

typedef __hip_bfloat16 bf16;
typedef __attribute__((ext_vector_type(8))) short short8;
typedef __attribute__((ext_vector_type(4))) float float4_t;

struct bf16x4 { bf16 a, b, c, d; };
struct alignas(16) bf8 { bf16 e[8]; };

__device__ __forceinline__ float b2f(bf16 u) {
    union { unsigned int i; float f; } c;
    c.i = ((unsigned int)__bfloat16_as_ushort(u)) << 16;
    return c.f;
}

__device__ __forceinline__ float lam_of(const float* beta, int head) {
    float lam = 1.0f - exp2f(-beta[head]);
    return fminf(fmaxf(lam, 1.1754944e-38f), 1.0f - 1e-9f);
}

// ---------------------------------------------------------------------------
// f32 -> bf16 conversion (4 elems/thread, n must be multiple of 1024)
// ---------------------------------------------------------------------------
__global__ __launch_bounds__(256) void cvt_f32_bf16(const float* __restrict__ in,
                                                    bf16* __restrict__ out, int n) {
    int i = (blockIdx.x * 256 + threadIdx.x) * 4;
    if (i >= n) return;
    float4 f = *(const float4*)(in + i);
    bf16x4 o;
    o.a = __float2bfloat16(f.x);
    o.b = __float2bfloat16(f.y);
    o.c = __float2bfloat16(f.z);
    o.d = __float2bfloat16(f.w);
    *(bf16x4*)(out + i) = o;
}

// 4 weight matrices (1M f32 each) -> contiguous bf16 (wq|wv|wg|wo). grid 4096.
__global__ __launch_bounds__(256) void cvt4_weights(const float* __restrict__ w0,
                                                    const float* __restrict__ w1,
                                                    const float* __restrict__ w2,
                                                    const float* __restrict__ w3,
                                                    bf16* __restrict__ o) {
    int which = blockIdx.x >> 10;
    int i = ((blockIdx.x & 1023) * 256 + threadIdx.x) * 4;
    const float* w = (which == 0) ? w0 : (which == 1) ? w1 : (which == 2) ? w2 : w3;
    float4 f = *(const float4*)(w + i);
    bf16x4 r;
    r.a = __float2bfloat16(f.x);
    r.b = __float2bfloat16(f.y);
    r.c = __float2bfloat16(f.z);
    r.d = __float2bfloat16(f.w);
    *(bf16x4*)(o + (size_t)which * 1048576 + i) = r;
}

// ---------------------------------------------------------------------------
// async 16B global -> LDS. NOTE: the intrinsic's imm offset applies to BOTH
// the global and LDS address (LDS dest = M0 + offset + lane*16) — R4 failed
// because of this. Always pass 0 and advance the global pointer instead.
// ---------------------------------------------------------------------------
__device__ __forceinline__ void async16(const bf16* g, bf16* l) {
    __builtin_amdgcn_global_load_lds(
        (const __attribute__((address_space(1))) void*)g,
        (__attribute__((address_space(3))) void*)l,
        16, 0, 0);
}

// ---------------------------------------------------------------------------
// GEMM: C[M,N] = A[M,K] * B[N,K]^T  (row-major, K contiguous), ldc row stride.
// 128x128 tile, 256 threads (2x2 waves of 64x64), 16x16x32 bf16 MFMA.
// LDS chunk swizzle c = 4r + ((kg + (r>>1))&3) over 16B chunks: read groups
// of 16 lanes hit all 8 four-bank groups (2-way aliasing = free) vs 8-way
// for the linear layout. Staging keeps lane-linear LDS dests (required by
// the LDS-DMA hardware); only each thread's *global* kgroup is permuted.
// K-loop: offset-0 LDS-DMA + explicit pointer increments, no unrolling.
// ---------------------------------------------------------------------------
template <typename OutT, int KK>
__global__ __launch_bounds__(256) void gemm_bt(const bf16* __restrict__ A,
                                               const bf16* __restrict__ Bm,
                                               OutT* __restrict__ C,
                                               int M, int N, int ldc) {
    __shared__ bf16 sA[128 * 32];
    __shared__ bf16 sB[128 * 32];

    const int t    = threadIdx.x;
    const int lane = t & 63;
    const int wave = t >> 6;
    const int wm   = (wave >> 1) * 64;
    const int wn   = (wave & 1) * 64;

    const int bm = blockIdx.x;
    const int bn = blockIdx.y;

    // staging: thread t owns chunks c1=t (rows 0..63) and c2=t+256 (rows 64..127)
    // chunk c -> row r=c>>2, global kgroup g=((c&3)-(c>>3))&3 (inverse swizzle)
    const int c1 = t, c2 = t + 256;
    const int r1 = c1 >> 2, g1 = ((c1 & 3) - (c1 >> 3)) & 3;
    const int r2 = c2 >> 2, g2 = ((c2 & 3) - (c2 >> 3)) & 3;
    const bf16* gA1 = A  + (size_t)(bm * 128 + r1) * KK + g1 * 8;
    const bf16* gA2 = A  + (size_t)(bm * 128 + r2) * KK + g2 * 8;
    const bf16* gB1 = Bm + (size_t)(bn * 128 + r1) * KK + g1 * 8;
    const bf16* gB2 = Bm + (size_t)(bn * 128 + r2) * KK + g2 * 8;
    bf16* lA1 = sA + c1 * 8;
    bf16* lA2 = sA + c2 * 8;
    bf16* lB1 = sB + c1 * 8;
    bf16* lB2 = sB + c2 * 8;

    // loop-invariant LDS read addresses: row r, kgroup kg -> chunk 4r+((kg+(r>>1))&3)
    const int kg = lane >> 4;
    const bf16* ra[4];
    const bf16* rb[4];
#pragma unroll
    for (int mi = 0; mi < 4; ++mi) {
        int r = wm + (lane & 15) + mi * 16;
        ra[mi] = sA + (r * 4 + ((kg + (r >> 1)) & 3)) * 8;
    }
#pragma unroll
    for (int ni = 0; ni < 4; ++ni) {
        int r = wn + (lane & 15) + ni * 16;
        rb[ni] = sB + (r * 4 + ((kg + (r >> 1)) & 3)) * 8;
    }

    float4_t acc[4][4] = {};

#pragma unroll 1
    for (int it = 0; it < KK / 32; ++it) {
        async16(gA1, lA1);
        async16(gA2, lA2);
        async16(gB1, lB1);
        async16(gB2, lB2);
        gA1 += 32; gA2 += 32; gB1 += 32; gB2 += 32;
        __syncthreads();

        short8 af[4], bfr[4];
#pragma unroll
        for (int mi = 0; mi < 4; ++mi) af[mi]  = *(const short8*)ra[mi];
#pragma unroll
        for (int ni = 0; ni < 4; ++ni) bfr[ni] = *(const short8*)rb[ni];

#pragma unroll
        for (int mi = 0; mi < 4; ++mi)
#pragma unroll
            for (int ni = 0; ni < 4; ++ni)
                acc[mi][ni] = __builtin_amdgcn_mfma_f32_16x16x32_bf16(
                    af[mi], bfr[ni], acc[mi][ni], 0, 0, 0);
        __syncthreads();
    }

    const int rbase = bm * 128 + wm + ((lane >> 4) << 2);
    const int cbase = bn * 128 + wn + (lane & 15);
#pragma unroll
    for (int mi = 0; mi < 4; ++mi) {
#pragma unroll
        for (int ni = 0; ni < 4; ++ni) {
#pragma unroll
            for (int r = 0; r < 4; ++r) {
                int row = rbase + mi * 16 + r;
                int col = cbase + ni * 16;
                C[(size_t)row * ldc + col] = (OutT)acc[mi][ni][r];
            }
        }
    }
}

// ---------------------------------------------------------------------------
// Exact two-phase retention scan over fused qvg layout (row stride 3072).
// Phase A: per-chunk local scan -> chunk sums S. Phase B: carry scan over
// chunks. Phase C: re-scan from carry, write ret = q*s in place over q.
// ---------------------------------------------------------------------------
__global__ __launch_bounds__(64) void scan_chunksum(const bf16* __restrict__ qvg,
                                                    const float* __restrict__ beta,
                                                    float* __restrict__ S) {
    const int c    = blockIdx.x;
    const int half = blockIdx.y;
    const int b    = blockIdx.z;
    const int tid  = threadIdx.x;
    const int dh0  = half * 512 + tid * 8;
    const float lam = lam_of(beta, dh0 >> 6);

    const bf16* vp = qvg + 1024 + ((size_t)(b * LL + c * SCC)) * LDQVG + dh0;

    float s[8] = {};
#pragma unroll
    for (int t = 0; t < SCC; ++t) {
        bf8 vv = *(const bf8*)(vp + (size_t)t * LDQVG);
#pragma unroll
        for (int j = 0; j < 8; ++j)
            s[j] = fmaf(s[j], lam, b2f(vv.e[j]));
    }

    float* sp = S + ((size_t)(b * NCHUNK + c)) * DD + dh0;
    float4 lo = {s[0], s[1], s[2], s[3]};
    float4 hi = {s[4], s[5], s[6], s[7]};
    *(float4*)(sp)     = lo;
    *(float4*)(sp + 4) = hi;
}

__global__ __launch_bounds__(64) void scan_carry(const float* __restrict__ S,
                                                 float* __restrict__ T,
                                                 const float* __restrict__ beta) {
    const int gid = blockIdx.x * 64 + threadIdx.x;  // 0..4095
    const int b = gid >> 10;
    const int f = gid & 1023;
    const float lam  = lam_of(beta, f >> 6);
    const float lamC = powf(lam, (float)SCC);

    const size_t base = (size_t)b * NCHUNK * DD + f;
    float t = 0.0f;
    for (int c = 0; c < NCHUNK; ++c) {
        float s = S[base + (size_t)c * DD];
        T[base + (size_t)c * DD] = t;
        t = fmaf(t, lamC, s);
    }
}

__global__ __launch_bounds__(64) void scan_apply(bf16* __restrict__ qvg,
                                                 const float* __restrict__ beta,
                                                 const float* __restrict__ T) {
    const int c    = blockIdx.x;
    const int half = blockIdx.y;
    const int b    = blockIdx.z;
    const int tid  = threadIdx.x;
    const int dh0  = half * 512 + tid * 8;
    const float lam = lam_of(beta, dh0 >> 6);

    const float* tp = T + ((size_t)(b * NCHUNK + c)) * DD + dh0;
    float4 lo = *(const float4*)(tp);
    float4 hi = *(const float4*)(tp + 4);
    float s[8] = {lo.x, lo.y, lo.z, lo.w, hi.x, hi.y, hi.z, hi.w};

    bf16* qp = qvg + ((size_t)(b * LL + c * SCC)) * LDQVG + dh0;

#pragma unroll
    for (int t = 0; t < SCC; ++t) {
        const size_t off = (size_t)t * LDQVG;
        bf8 vv = *(const bf8*)(qp + 1024 + off);
        bf8 qq = *(const bf8*)(qp + off);
        bf8 o;
#pragma unroll
        for (int j = 0; j < 8; ++j) {
            s[j] = fmaf(s[j], lam, b2f(vv.e[j]));
            o.e[j] = __float2bfloat16(b2f(qq.e[j]) * s[j]);
        }
        *(bf8*)(qp + off) = o;
    }
}

// ---------------------------------------------------------------------------
// Fused LayerNorm(ret) * SiLU(gpre) -> z (bf16, contiguous [M,1024]).
// ---------------------------------------------------------------------------
__global__ __launch_bounds__(256) void ln_gate(const bf16* __restrict__ qvg,
                                               const float* __restrict__ gamma,
                                               const float* __restrict__ betaln,
                                               bf16* __restrict__ z) {
    const int row  = blockIdx.x;
    const int tid  = threadIdx.x;
    const int lane = tid & 63;
    const int wave = tid >> 6;
    const size_t rbase = (size_t)row * LDQVG + tid * 4;

    bf16x4 rv = *(const bf16x4*)(qvg + rbase);
    float x0 = b2f(rv.a), x1 = b2f(rv.b), x2 = b2f(rv.c), x3 = b2f(rv.d);

    float s  = x0 + x1 + x2 + x3;
    float s2 = x0 * x0 + x1 * x1 + x2 * x2 + x3 * x3;
#pragma unroll
    for (int off = 32; off >= 1; off >>= 1) {
        s  += __shfl_xor(s, off, 64);
        s2 += __shfl_xor(s2, off, 64);
    }
    __shared__ float red[8];
    if (lane == 0) { red[wave] = s; red[wave + 4] = s2; }
    __syncthreads();
    s  = red[0] + red[1] + red[2] + red[3];
    s2 = red[4] + red[5] + red[6] + red[7];

    const float mu   = s * (1.0f / DD);
    const float var  = s2 * (1.0f / DD) - mu * mu;
    const float rstd = rsqrtf(var + LN_EPS);

    bf16x4 gv = *(const bf16x4*)(qvg + rbase + 2048);
    float4 gm = *(const float4*)(gamma + tid * 4);
    float4 bt = *(const float4*)(betaln + tid * 4);

    float xs[4]  = {x0, x1, x2, x3};
    float gs[4]  = {b2f(gv.a), b2f(gv.b), b2f(gv.c), b2f(gv.d)};
    float gmm[4] = {gm.x, gm.y, gm.z, gm.w};
    float btt[4] = {bt.x, bt.y, bt.z, bt.w};

    bf16x4 o;
    bf16* op = &o.a;
#pragma unroll
    for (int j = 0; j < 4; ++j) {
        float y  = (xs[j] - mu) * rstd * gmm[j] + btt[j];
        float g  = gs[j];
        float sg = g / (1.0f + expf(-g));
        op[j] = __float2bfloat16(y * sg);
    }
    *(bf16x4*)(z + (size_t)row * DD + tid * 4) = o;
}

// ---------------------------------------------------------------------------
// launch
// ---------------------------------------------------------------------------
extern "C" void kernel_launch(void* const* d_in, const int* in_sizes, int n_in,
                              void* d_out, int out_size, void* d_ws, size_t ws_size,
                              hipStream_t stream) {
    const float* x     = (const float*)d_in[0];
    const float* Wq    = (const float*)d_in[1];
    const float* Wv    = (const float*)d_in[2];
    const float* Wo    = (const float*)d_in[3];
    const float* Wg    = (const float*)d_in[4];
    const float* beta  = (const float*)d_in[5];
    const float* ln_g  = (const float*)d_in[6];
    const float* ln_b  = (const float*)d_in[7];
    float* out = (float*)d_out;

    char* ws = (char*)d_ws;
    // workspace layout (bytes):
    //   xb  : 32MB @ 0      bf16 x for the QVG GEMM; dead afterwards. Region
    //                       reused: S (4MB @0), T (4MB @4MB) during scan,
    //                       then z (32MB @0) from ln_gate on.
    //   wqb : 6MB  @ 32MB   wq|wv|wg contiguous (fused N=3072 GEMM B)
    //   wob : 2MB  @ 38MB
    //   qvg : 96MB @ 40MB   [M,3072] = q|v|g per row      -> total 136MB
    bf16*  xb   = (bf16*)ws;
    float* Sbuf = (float*)ws;                                  // 4 MB (alias xb)
    float* Tbuf = (float*)(ws + (size_t)4 * 1024 * 1024);      // 4 MB (alias xb)
    bf16*  wqb  = (bf16*)(ws + (size_t)32 * 1024 * 1024);
    bf16*  wob  = wqb + 3 * 1048576;
    bf16*  qvg  = (bf16*)(ws + (size_t)40 * 1024 * 1024);
    bf16*  zb   = xb;   // alias: xb/S/T dead by ln_gate

    cvt_f32_bf16<<<dim3((MM * DD) / 1024), dim3(256), 0, stream>>>(x, xb, MM * DD);
    cvt4_weights<<<dim3(4096), dim3(256), 0, stream>>>(Wq, Wv, Wg, Wo, wqb);

    // fused QVG GEMM: [M,1024] x [3072,1024]^T -> [M,3072]
    gemm_bt<bf16, DD><<<dim3(MM / 128, LDQVG / 128), dim3(256), 0, stream>>>(
        xb, wqb, qvg, MM, LDQVG, LDQVG);

    // exact two-phase retention scan
    scan_chunksum<<<dim3(NCHUNK, 2, BB), dim3(64), 0, stream>>>(qvg, beta, Sbuf);
    scan_carry<<<dim3(64), dim3(64), 0, stream>>>(Sbuf, Tbuf, beta);
    scan_apply<<<dim3(NCHUNK, 2, BB), dim3(64), 0, stream>>>(qvg, beta, Tbuf);

    ln_gate<<<dim3(MM), dim3(256), 0, stream>>>(qvg, ln_g, ln_b, zb);

    gemm_bt<float, DD><<<dim3(MM / 128, DD / 128), dim3(256), 0, stream>>>(
        zb, wob, out, MM, DD, DD);
}

// Round 6
// 349.826 us; speedup vs baseline: 1.4398x; 1.0807x over previous
//
#include <hip/hip_runtime.h>
#include <hip/hip_bf16.h>
#include <cfloat>

// Problem constants (reference: B=4, L=4096, D=1024, H=16, Dh=64)
#define BB 4
#define LL 4096
#define DD 1024
#define HH 16
#define DHH 64
#define MM (BB * LL)          // 16384 rows
#define LN_EPS 1e-5f
#define LDQVG 3072            // fused q|v|g row stride
#define SCC 16                // scan chunk length
#define NCHUNK (LL / SCC)     // 256 chunks per batch

typedef __hip_bfloat16 bf16;
typedef __attribute__((ext_vector_type(8))) short short8;
typedef __attribute__((ext_vector_type(16))) float float16_t;

struct bf16x4 { bf16 a, b, c, d; };
struct alignas(16) bf8 { bf16 e[8]; };

__device__ __forceinline__ float b2f(bf16 u) {
    union { unsigned int i; float f; } c;
    c.i = ((unsigned int)__bfloat16_as_ushort(u)) << 16;
    return c.f;
}

__device__ __forceinline__ float lam_of(const float* beta, int head) {
    float lam = 1.0f - exp2f(-beta[head]);
    return fminf(fmaxf(lam, 1.1754944e-38f), 1.0f - 1e-9f);
}

// ---------------------------------------------------------------------------
// f32 -> bf16 conversion (4 elems/thread, n must be multiple of 1024)
// ---------------------------------------------------------------------------
__global__ __launch_bounds__(256) void cvt_f32_bf16(const float* __restrict__ in,
                                                    bf16* __restrict__ out, int n) {
    int i = (blockIdx.x * 256 + threadIdx.x) * 4;
    if (i >= n) return;
    float4 f = *(const float4*)(in + i);
    bf16x4 o;
    o.a = __float2bfloat16(f.x);
    o.b = __float2bfloat16(f.y);
    o.c = __float2bfloat16(f.z);
    o.d = __float2bfloat16(f.w);
    *(bf16x4*)(out + i) = o;
}

// 4 weight matrices (1M f32 each) -> contiguous bf16 (wq|wv|wg|wo). grid 4096.
__global__ __launch_bounds__(256) void cvt4_weights(const float* __restrict__ w0,
                                                    const float* __restrict__ w1,
                                                    const float* __restrict__ w2,
                                                    const float* __restrict__ w3,
                                                    bf16* __restrict__ o) {
    int which = blockIdx.x >> 10;
    int i = ((blockIdx.x & 1023) * 256 + threadIdx.x) * 4;
    const float* w = (which == 0) ? w0 : (which == 1) ? w1 : (which == 2) ? w2 : w3;
    float4 f = *(const float4*)(w + i);
    bf16x4 r;
    r.a = __float2bfloat16(f.x);
    r.b = __float2bfloat16(f.y);
    r.c = __float2bfloat16(f.z);
    r.d = __float2bfloat16(f.w);
    *(bf16x4*)(o + (size_t)which * 1048576 + i) = r;
}

// ---------------------------------------------------------------------------
// async 16B global -> LDS. NOTE: imm offset applies to BOTH global and LDS
// addresses (R4 failure) — always pass 0, advance global pointers manually.
// ---------------------------------------------------------------------------
__device__ __forceinline__ void async16(const bf16* g, bf16* l) {
    __builtin_amdgcn_global_load_lds(
        (const __attribute__((address_space(1))) void*)g,
        (__attribute__((address_space(3))) void*)l,
        16, 0, 0);
}

// ---------------------------------------------------------------------------
// GEMM: C[M,N] = A[M,K] * B[N,K]^T  (row-major, K contiguous), ldc row stride.
// 128x128 tile, 256 threads = 4 waves (2x2 of 64x64). Each wave: 2x2 of
// v_mfma_f32_32x32x16_bf16 (64 f32 acc/lane). BK=64 per barrier interval:
// 16 MFMA x 8cyc = 128 matrix-cycles per barrier (2x the BK=32 structure).
// LDS row = 64 elems = 8 chunks of 16B; chunk swizzle p = (kc + r) & 7:
// read phases put 2 lanes per 4-bank group = conflict-free (m136); staging
// keeps lane-linear LDS dests (DMA requirement), global kgroup inverse-
// permuted per thread, 8 threads still cover one 128B row segment coalesced.
// Fragment layouts: A/B [m=lane&31][k=(lane>>5)*8+j]; C/D col=lane&31,
// row=(reg&3)+8*(reg>>2)+4*(lane>>5)  (HW-verified m74/m101).
// ---------------------------------------------------------------------------
template <typename OutT, int KK>
__global__ __launch_bounds__(256) void gemm_bt(const bf16* __restrict__ A,
                                               const bf16* __restrict__ Bm,
                                               OutT* __restrict__ C,
                                               int M, int N, int ldc) {
    __shared__ bf16 sA[128 * 64];
    __shared__ bf16 sB[128 * 64];

    const int t    = threadIdx.x;
    const int lane = t & 63;
    const int wave = t >> 6;
    const int wm   = (wave >> 1) * 64;
    const int wn   = (wave & 1) * 64;

    const int bm = blockIdx.x;
    const int bn = blockIdx.y;

    // staging: 1024 chunks (16B) per matrix; thread t owns c = t + j*256.
    // chunk c: row r=c>>3, phys slot p=c&7, logical kgroup g=((c&7)-(r&7))&7.
    const bf16* gA[4];
    const bf16* gB[4];
    bf16* lA[4];
    bf16* lB[4];
#pragma unroll
    for (int j = 0; j < 4; ++j) {
        int c = t + j * 256;
        int r = c >> 3;
        int g = ((c & 7) - (r & 7)) & 7;
        gA[j] = A  + (size_t)(bm * 128 + r) * KK + g * 8;
        gB[j] = Bm + (size_t)(bn * 128 + r) * KK + g * 8;
        lA[j] = sA + c * 8;
        lB[j] = sB + c * 8;
    }

    // loop-invariant LDS read addrs: row r, logical kgroup kc=2*tk+(lane>>5)
    // -> element offset (r*8 + ((kc + r)&7)) * 8
    const int kh = lane >> 5;           // k-half within fragment
    const bf16* rdA[2][4];
    const bf16* rdB[2][4];
#pragma unroll
    for (int mi = 0; mi < 2; ++mi) {
        int r = wm + (lane & 31) + mi * 32;
#pragma unroll
        for (int tk = 0; tk < 4; ++tk) {
            int kc = tk * 2 + kh;
            rdA[mi][tk] = sA + (r * 8 + ((kc + r) & 7)) * 8;
        }
    }
#pragma unroll
    for (int ni = 0; ni < 2; ++ni) {
        int r = wn + (lane & 31) + ni * 32;
#pragma unroll
        for (int tk = 0; tk < 4; ++tk) {
            int kc = tk * 2 + kh;
            rdB[ni][tk] = sB + (r * 8 + ((kc + r) & 7)) * 8;
        }
    }

    float16_t acc[2][2] = {};

#pragma unroll 1
    for (int it = 0; it < KK / 64; ++it) {
#pragma unroll
        for (int j = 0; j < 4; ++j) async16(gA[j], lA[j]);
#pragma unroll
        for (int j = 0; j < 4; ++j) async16(gB[j], lB[j]);
#pragma unroll
        for (int j = 0; j < 4; ++j) { gA[j] += 64; gB[j] += 64; }
        __syncthreads();

#pragma unroll
        for (int tk = 0; tk < 4; ++tk) {
            short8 a0 = *(const short8*)rdA[0][tk];
            short8 a1 = *(const short8*)rdA[1][tk];
            short8 b0 = *(const short8*)rdB[0][tk];
            short8 b1 = *(const short8*)rdB[1][tk];
            acc[0][0] = __builtin_amdgcn_mfma_f32_32x32x16_bf16(a0, b0, acc[0][0], 0, 0, 0);
            acc[0][1] = __builtin_amdgcn_mfma_f32_32x32x16_bf16(a0, b1, acc[0][1], 0, 0, 0);
            acc[1][0] = __builtin_amdgcn_mfma_f32_32x32x16_bf16(a1, b0, acc[1][0], 0, 0, 0);
            acc[1][1] = __builtin_amdgcn_mfma_f32_32x32x16_bf16(a1, b1, acc[1][1], 0, 0, 0);
        }
        __syncthreads();
    }

    // epilogue: C/D col=lane&31, row=(reg&3)+8*(reg>>2)+4*(lane>>5)
    const int col0 = bn * 128 + wn + (lane & 31);
    const int row0 = bm * 128 + wm + 4 * (lane >> 5);
#pragma unroll
    for (int mi = 0; mi < 2; ++mi) {
#pragma unroll
        for (int ni = 0; ni < 2; ++ni) {
#pragma unroll
            for (int reg = 0; reg < 16; ++reg) {
                int row = row0 + mi * 32 + (reg & 3) + 8 * (reg >> 2);
                C[(size_t)row * ldc + col0 + ni * 32] = (OutT)acc[mi][ni][reg];
            }
        }
    }
}

// ---------------------------------------------------------------------------
// Exact two-phase retention scan over fused qvg layout (row stride 3072).
// Phase A: per-chunk local scan -> chunk sums S. Phase B: carry scan over
// chunks. Phase C: re-scan from carry, write ret = q*s in place over q.
// ---------------------------------------------------------------------------
__global__ __launch_bounds__(64) void scan_chunksum(const bf16* __restrict__ qvg,
                                                    const float* __restrict__ beta,
                                                    float* __restrict__ S) {
    const int c    = blockIdx.x;
    const int half = blockIdx.y;
    const int b    = blockIdx.z;
    const int tid  = threadIdx.x;
    const int dh0  = half * 512 + tid * 8;
    const float lam = lam_of(beta, dh0 >> 6);

    const bf16* vp = qvg + 1024 + ((size_t)(b * LL + c * SCC)) * LDQVG + dh0;

    float s[8] = {};
#pragma unroll
    for (int t = 0; t < SCC; ++t) {
        bf8 vv = *(const bf8*)(vp + (size_t)t * LDQVG);
#pragma unroll
        for (int j = 0; j < 8; ++j)
            s[j] = fmaf(s[j], lam, b2f(vv.e[j]));
    }

    float* sp = S + ((size_t)(b * NCHUNK + c)) * DD + dh0;
    float4 lo = {s[0], s[1], s[2], s[3]};
    float4 hi = {s[4], s[5], s[6], s[7]};
    *(float4*)(sp)     = lo;
    *(float4*)(sp + 4) = hi;
}

__global__ __launch_bounds__(64) void scan_carry(const float* __restrict__ S,
                                                 float* __restrict__ T,
                                                 const float* __restrict__ beta) {
    const int gid = blockIdx.x * 64 + threadIdx.x;  // 0..4095
    const int b = gid >> 10;
    const int f = gid & 1023;
    const float lam  = lam_of(beta, f >> 6);
    const float lamC = powf(lam, (float)SCC);

    const size_t base = (size_t)b * NCHUNK * DD + f;
    float t = 0.0f;
    for (int c = 0; c < NCHUNK; ++c) {
        float s = S[base + (size_t)c * DD];
        T[base + (size_t)c * DD] = t;
        t = fmaf(t, lamC, s);
    }
}

__global__ __launch_bounds__(64) void scan_apply(bf16* __restrict__ qvg,
                                                 const float* __restrict__ beta,
                                                 const float* __restrict__ T) {
    const int c    = blockIdx.x;
    const int half = blockIdx.y;
    const int b    = blockIdx.z;
    const int tid  = threadIdx.x;
    const int dh0  = half * 512 + tid * 8;
    const float lam = lam_of(beta, dh0 >> 6);

    const float* tp = T + ((size_t)(b * NCHUNK + c)) * DD + dh0;
    float4 lo = *(const float4*)(tp);
    float4 hi = *(const float4*)(tp + 4);
    float s[8] = {lo.x, lo.y, lo.z, lo.w, hi.x, hi.y, hi.z, hi.w};

    bf16* qp = qvg + ((size_t)(b * LL + c * SCC)) * LDQVG + dh0;

#pragma unroll
    for (int t = 0; t < SCC; ++t) {
        const size_t off = (size_t)t * LDQVG;
        bf8 vv = *(const bf8*)(qp + 1024 + off);
        bf8 qq = *(const bf8*)(qp + off);
        bf8 o;
#pragma unroll
        for (int j = 0; j < 8; ++j) {
            s[j] = fmaf(s[j], lam, b2f(vv.e[j]));
            o.e[j] = __float2bfloat16(b2f(qq.e[j]) * s[j]);
        }
        *(bf8*)(qp + off) = o;
    }
}

// ---------------------------------------------------------------------------
// Fused LayerNorm(ret) * SiLU(gpre) -> z (bf16, contiguous [M,1024]).
// ---------------------------------------------------------------------------
__global__ __launch_bounds__(256) void ln_gate(const bf16* __restrict__ qvg,
                                               const float* __restrict__ gamma,
                                               const float* __restrict__ betaln,
                                               bf16* __restrict__ z) {
    const int row  = blockIdx.x;
    const int tid  = threadIdx.x;
    const int lane = tid & 63;
    const int wave = tid >> 6;
    const size_t rbase = (size_t)row * LDQVG + tid * 4;

    bf16x4 rv = *(const bf16x4*)(qvg + rbase);
    float x0 = b2f(rv.a), x1 = b2f(rv.b), x2 = b2f(rv.c), x3 = b2f(rv.d);

    float s  = x0 + x1 + x2 + x3;
    float s2 = x0 * x0 + x1 * x1 + x2 * x2 + x3 * x3;
#pragma unroll
    for (int off = 32; off >= 1; off >>= 1) {
        s  += __shfl_xor(s, off, 64);
        s2 += __shfl_xor(s2, off, 64);
    }
    __shared__ float red[8];
    if (lane == 0) { red[wave] = s; red[wave + 4] = s2; }
    __syncthreads();
    s  = red[0] + red[1] + red[2] + red[3];
    s2 = red[4] + red[5] + red[6] + red[7];

    const float mu   = s * (1.0f / DD);
    const float var  = s2 * (1.0f / DD) - mu * mu;
    const float rstd = rsqrtf(var + LN_EPS);

    bf16x4 gv = *(const bf16x4*)(qvg + rbase + 2048);
    float4 gm = *(const float4*)(gamma + tid * 4);
    float4 bt = *(const float4*)(betaln + tid * 4);

    float xs[4]  = {x0, x1, x2, x3};
    float gs[4]  = {b2f(gv.a), b2f(gv.b), b2f(gv.c), b2f(gv.d)};
    float gmm[4] = {gm.x, gm.y, gm.z, gm.w};
    float btt[4] = {bt.x, bt.y, bt.z, bt.w};

    bf16x4 o;
    bf16* op = &o.a;
#pragma unroll
    for (int j = 0; j < 4; ++j) {
        float y  = (xs[j] - mu) * rstd * gmm[j] + btt[j];
        float g  = gs[j];
        float sg = g / (1.0f + expf(-g));
        op[j] = __float2bfloat16(y * sg);
    }
    *(bf16x4*)(z + (size_t)row * DD + tid * 4) = o;
}

// ---------------------------------------------------------------------------
// launch
// ---------------------------------------------------------------------------
extern "C" void kernel_launch(void* const* d_in, const int* in_sizes, int n_in,
                              void* d_out, int out_size, void* d_ws, size_t ws_size,
                              hipStream_t stream) {
    const float* x     = (const float*)d_in[0];
    const float* Wq    = (const float*)d_in[1];
    const float* Wv    = (const float*)d_in[2];
    const float* Wo    = (const float*)d_in[3];
    const float* Wg    = (const float*)d_in[4];
    const float* beta  = (const float*)d_in[5];
    const float* ln_g  = (const float*)d_in[6];
    const float* ln_b  = (const float*)d_in[7];
    float* out = (float*)d_out;

    char* ws = (char*)d_ws;
    // workspace layout (bytes):
    //   xb  : 32MB @ 0      bf16 x for the QVG GEMM; dead afterwards. Region
    //                       reused: S (4MB @0), T (4MB @4MB) during scan,
    //                       then z (32MB @0) from ln_gate on.
    //   wqb : 6MB  @ 32MB   wq|wv|wg contiguous (fused N=3072 GEMM B)
    //   wob : 2MB  @ 38MB
    //   qvg : 96MB @ 40MB   [M,3072] = q|v|g per row      -> total 136MB
    bf16*  xb   = (bf16*)ws;
    float* Sbuf = (float*)ws;                                  // 4 MB (alias xb)
    float* Tbuf = (float*)(ws + (size_t)4 * 1024 * 1024);      // 4 MB (alias xb)
    bf16*  wqb  = (bf16*)(ws + (size_t)32 * 1024 * 1024);
    bf16*  wob  = wqb + 3 * 1048576;
    bf16*  qvg  = (bf16*)(ws + (size_t)40 * 1024 * 1024);
    bf16*  zb   = xb;   // alias: xb/S/T dead by ln_gate

    cvt_f32_bf16<<<dim3((MM * DD) / 1024), dim3(256), 0, stream>>>(x, xb, MM * DD);
    cvt4_weights<<<dim3(4096), dim3(256), 0, stream>>>(Wq, Wv, Wg, Wo, wqb);

    // fused QVG GEMM: [M,1024] x [3072,1024]^T -> [M,3072]
    gemm_bt<bf16, DD><<<dim3(MM / 128, LDQVG / 128), dim3(256), 0, stream>>>(
        xb, wqb, qvg, MM, LDQVG, LDQVG);

    // exact two-phase retention scan
    scan_chunksum<<<dim3(NCHUNK, 2, BB), dim3(64), 0, stream>>>(qvg, beta, Sbuf);
    scan_carry<<<dim3(64), dim3(64), 0, stream>>>(Sbuf, Tbuf, beta);
    scan_apply<<<dim3(NCHUNK, 2, BB), dim3(64), 0, stream>>>(qvg, beta, Tbuf);

    ln_gate<<<dim3(MM), dim3(256), 0, stream>>>(qvg, ln_g, ln_b, zb);

    gemm_bt<float, DD><<<dim3(MM / 128, DD / 128), dim3(256), 0, stream>>>(
        zb, wob, out, MM, DD, DD);
}

// Round 7
// 348.703 us; speedup vs baseline: 1.4445x; 1.0032x over previous
//
#include <hip/hip_runtime.h>
#include <hip/hip_bf16.h>
#include <cfloat>

// Problem constants (reference: B=4, L=4096, D=1024, H=16, Dh=64)
#define BB 4
#define LL 4096
#define DD 1024
#define HH 16
#define DHH 64
#define MM (BB * LL)          // 16384 rows
#define LN_EPS 1e-5f
#define LDQVG 3072            // fused q|v|g row stride
#define SCC 16                // scan chunk length
#define NCHUNK (LL / SCC)     // 256 chunks per batch

typedef __hip_bfloat16 bf16;
typedef __attribute__((ext_vector_type(8))) short short8;
typedef __attribute__((ext_vector_type(16))) float float16_t;

struct bf16x4 { bf16 a, b, c, d; };
struct alignas(16) bf8 { bf16 e[8]; };

__device__ __forceinline__ float b2f(bf16 u) {
    union { unsigned int i; float f; } c;
    c.i = ((unsigned int)__bfloat16_as_ushort(u)) << 16;
    return c.f;
}

__device__ __forceinline__ float lam_of(const float* beta, int head) {
    float lam = 1.0f - exp2f(-beta[head]);
    return fminf(fmaxf(lam, 1.1754944e-38f), 1.0f - 1e-9f);
}

// ---------------------------------------------------------------------------
// All f32->bf16 conversions in ONE dispatch: x (16384 blocks) then the four
// weight matrices (4*1024 blocks) into contiguous wq|wv|wg|wo.
// ---------------------------------------------------------------------------
__global__ __launch_bounds__(256) void cvt_all(const float* __restrict__ x,
                                               const float* __restrict__ wq,
                                               const float* __restrict__ wv,
                                               const float* __restrict__ wg,
                                               const float* __restrict__ wo,
                                               bf16* __restrict__ xb,
                                               bf16* __restrict__ wb) {
    const int blk = blockIdx.x;
    const float* src;
    bf16* dst;
    size_t off;
    if (blk < 16384) {
        src = x; dst = xb; off = (size_t)blk * 1024;
    } else {
        int wblk  = blk - 16384;
        int which = wblk >> 10;
        src = (which == 0) ? wq : (which == 1) ? wv : (which == 2) ? wg : wo;
        dst = wb + (size_t)which * 1048576;
        off = (size_t)(wblk & 1023) * 1024;
    }
    size_t i = off + threadIdx.x * 4;
    float4 f = *(const float4*)(src + i);
    bf16x4 o;
    o.a = __float2bfloat16(f.x);
    o.b = __float2bfloat16(f.y);
    o.c = __float2bfloat16(f.z);
    o.d = __float2bfloat16(f.w);
    *(bf16x4*)(dst + i) = o;
}

// ---------------------------------------------------------------------------
// async 16B global -> LDS. NOTE: imm offset applies to BOTH global and LDS
// addresses (R4 failure) — always pass 0, advance global pointers manually.
// ---------------------------------------------------------------------------
__device__ __forceinline__ void async16(const bf16* g, bf16* l) {
    __builtin_amdgcn_global_load_lds(
        (const __attribute__((address_space(1))) void*)g,
        (__attribute__((address_space(3))) void*)l,
        16, 0, 0);
}

// ---------------------------------------------------------------------------
// GEMM: C[M,N] = A[M,K] * B[N,K]^T  (row-major, K contiguous), ldc row stride.
// 128x128 tile, 256 threads = 4 waves (2x2 of 64x64). Each wave: 2x2 of
// v_mfma_f32_32x32x16_bf16 (64 f32 acc/lane). BK=64 per barrier interval.
// At 849 TF this sits on the documented m97-class plateau (MfmaUtil 38,
// VALUBusy 17, barrier-drain bound) — do not tweak further at source level.
// ---------------------------------------------------------------------------
template <typename OutT, int KK>
__global__ __launch_bounds__(256) void gemm_bt(const bf16* __restrict__ A,
                                               const bf16* __restrict__ Bm,
                                               OutT* __restrict__ C,
                                               int M, int N, int ldc) {
    __shared__ bf16 sA[128 * 64];
    __shared__ bf16 sB[128 * 64];

    const int t    = threadIdx.x;
    const int lane = t & 63;
    const int wave = t >> 6;
    const int wm   = (wave >> 1) * 64;
    const int wn   = (wave & 1) * 64;

    const int bm = blockIdx.x;
    const int bn = blockIdx.y;

    // staging: 1024 chunks (16B) per matrix; thread t owns c = t + j*256.
    // chunk c: row r=c>>3, phys slot p=c&7, logical kgroup g=((c&7)-(r&7))&7.
    const bf16* gA[4];
    const bf16* gB[4];
    bf16* lA[4];
    bf16* lB[4];
#pragma unroll
    for (int j = 0; j < 4; ++j) {
        int c = t + j * 256;
        int r = c >> 3;
        int g = ((c & 7) - (r & 7)) & 7;
        gA[j] = A  + (size_t)(bm * 128 + r) * KK + g * 8;
        gB[j] = Bm + (size_t)(bn * 128 + r) * KK + g * 8;
        lA[j] = sA + c * 8;
        lB[j] = sB + c * 8;
    }

    // loop-invariant LDS read addrs: row r, logical kgroup kc=2*tk+(lane>>5)
    // -> element offset (r*8 + ((kc + r)&7)) * 8
    const int kh = lane >> 5;           // k-half within fragment
    const bf16* rdA[2][4];
    const bf16* rdB[2][4];
#pragma unroll
    for (int mi = 0; mi < 2; ++mi) {
        int r = wm + (lane & 31) + mi * 32;
#pragma unroll
        for (int tk = 0; tk < 4; ++tk) {
            int kc = tk * 2 + kh;
            rdA[mi][tk] = sA + (r * 8 + ((kc + r) & 7)) * 8;
        }
    }
#pragma unroll
    for (int ni = 0; ni < 2; ++ni) {
        int r = wn + (lane & 31) + ni * 32;
#pragma unroll
        for (int tk = 0; tk < 4; ++tk) {
            int kc = tk * 2 + kh;
            rdB[ni][tk] = sB + (r * 8 + ((kc + r) & 7)) * 8;
        }
    }

    float16_t acc[2][2] = {};

#pragma unroll 1
    for (int it = 0; it < KK / 64; ++it) {
#pragma unroll
        for (int j = 0; j < 4; ++j) async16(gA[j], lA[j]);
#pragma unroll
        for (int j = 0; j < 4; ++j) async16(gB[j], lB[j]);
#pragma unroll
        for (int j = 0; j < 4; ++j) { gA[j] += 64; gB[j] += 64; }
        __syncthreads();

#pragma unroll
        for (int tk = 0; tk < 4; ++tk) {
            short8 a0 = *(const short8*)rdA[0][tk];
            short8 a1 = *(const short8*)rdA[1][tk];
            short8 b0 = *(const short8*)rdB[0][tk];
            short8 b1 = *(const short8*)rdB[1][tk];
            acc[0][0] = __builtin_amdgcn_mfma_f32_32x32x16_bf16(a0, b0, acc[0][0], 0, 0, 0);
            acc[0][1] = __builtin_amdgcn_mfma_f32_32x32x16_bf16(a0, b1, acc[0][1], 0, 0, 0);
            acc[1][0] = __builtin_amdgcn_mfma_f32_32x32x16_bf16(a1, b0, acc[1][0], 0, 0, 0);
            acc[1][1] = __builtin_amdgcn_mfma_f32_32x32x16_bf16(a1, b1, acc[1][1], 0, 0, 0);
        }
        __syncthreads();
    }

    // epilogue: C/D col=lane&31, row=(reg&3)+8*(reg>>2)+4*(lane>>5)
    const int col0 = bn * 128 + wn + (lane & 31);
    const int row0 = bm * 128 + wm + 4 * (lane >> 5);
#pragma unroll
    for (int mi = 0; mi < 2; ++mi) {
#pragma unroll
        for (int ni = 0; ni < 2; ++ni) {
#pragma unroll
            for (int reg = 0; reg < 16; ++reg) {
                int row = row0 + mi * 32 + (reg & 3) + 8 * (reg >> 2);
                C[(size_t)row * ldc + col0 + ni * 32] = (OutT)acc[mi][ni][reg];
            }
        }
    }
}

// ---------------------------------------------------------------------------
// Exact two-phase retention scan over fused qvg layout (row stride 3072).
// Phase A: per-chunk local scan -> chunk sums S.
// Phase B: carry scan over chunks (8-wide prefetch pipeline).
// Phase C (fused with LN+gate below): re-scan from carry, LN, gate, write z.
// ---------------------------------------------------------------------------
__global__ __launch_bounds__(64) void scan_chunksum(const bf16* __restrict__ qvg,
                                                    const float* __restrict__ beta,
                                                    float* __restrict__ S) {
    const int c    = blockIdx.x;
    const int half = blockIdx.y;
    const int b    = blockIdx.z;
    const int tid  = threadIdx.x;
    const int dh0  = half * 512 + tid * 8;
    const float lam = lam_of(beta, dh0 >> 6);

    const bf16* vp = qvg + 1024 + ((size_t)(b * LL + c * SCC)) * LDQVG + dh0;

    float s[8] = {};
#pragma unroll
    for (int t = 0; t < SCC; ++t) {
        bf8 vv = *(const bf8*)(vp + (size_t)t * LDQVG);
#pragma unroll
        for (int j = 0; j < 8; ++j)
            s[j] = fmaf(s[j], lam, b2f(vv.e[j]));
    }

    float* sp = S + ((size_t)(b * NCHUNK + c)) * DD + dh0;
    float4 lo = {s[0], s[1], s[2], s[3]};
    float4 hi = {s[4], s[5], s[6], s[7]};
    *(float4*)(sp)     = lo;
    *(float4*)(sp + 4) = hi;
}

// Serial carry over 256 chunks, 8-wide load prefetch to break the
// latency chain (loads for batch i+1 are independent of the t-recurrence).
__global__ __launch_bounds__(64) void scan_carry(const float* __restrict__ S,
                                                 float* __restrict__ T,
                                                 const float* __restrict__ beta) {
    const int gid = blockIdx.x * 64 + threadIdx.x;  // 0..4095
    const int b = gid >> 10;
    const int f = gid & 1023;
    const float lam  = lam_of(beta, f >> 6);
    const float lamC = powf(lam, (float)SCC);

    const size_t base = (size_t)b * NCHUNK * DD + f;

    float v[8];
#pragma unroll
    for (int j = 0; j < 8; ++j) v[j] = S[base + (size_t)j * DD];

    float t = 0.0f;
    for (int c0 = 0; c0 < NCHUNK; c0 += 8) {
        float cur[8];
#pragma unroll
        for (int j = 0; j < 8; ++j) cur[j] = v[j];
        if (c0 + 8 < NCHUNK) {
#pragma unroll
            for (int j = 0; j < 8; ++j)
                v[j] = S[base + (size_t)(c0 + 8 + j) * DD];
        }
#pragma unroll
        for (int j = 0; j < 8; ++j) {
            T[base + (size_t)(c0 + j) * DD] = t;
            t = fmaf(t, lamC, cur[j]);
        }
    }
}

// ---------------------------------------------------------------------------
// Fused: re-scan chunk from carry T -> ret (kept in LDS), per-row LayerNorm,
// SiLU gate, write z (bf16, contiguous [M,1024]). ret never touches HBM.
// grid (NCHUNK, BB), 128 threads (2 waves). LDS 16 rows x 1024 bf16 = 32KB.
// ---------------------------------------------------------------------------
__global__ __launch_bounds__(128) void scan_apply_ln(const bf16* __restrict__ qvg,
                                                     const float* __restrict__ beta,
                                                     const float* __restrict__ T,
                                                     const float* __restrict__ gamma,
                                                     const float* __restrict__ betaln,
                                                     bf16* __restrict__ z) {
    __shared__ bf16 lds_ret[SCC][DD];   // 32 KB

    const int c   = blockIdx.x;
    const int b   = blockIdx.y;
    const int tid = threadIdx.x;        // 0..127
    const int f0  = tid * 8;
    const float lam = lam_of(beta, f0 >> 6);

    // ---- phase 1: local scan from carry, ret -> LDS ----
    const float* tp = T + ((size_t)(b * NCHUNK + c)) * DD + f0;
    float4 lo = *(const float4*)(tp);
    float4 hi = *(const float4*)(tp + 4);
    float s[8] = {lo.x, lo.y, lo.z, lo.w, hi.x, hi.y, hi.z, hi.w};

    const bf16* qp = qvg + ((size_t)(b * LL + c * SCC)) * LDQVG + f0;
#pragma unroll
    for (int t = 0; t < SCC; ++t) {
        const size_t off = (size_t)t * LDQVG;
        bf8 vv = *(const bf8*)(qp + 1024 + off);
        bf8 qq = *(const bf8*)(qp + off);
        bf8 o;
#pragma unroll
        for (int j = 0; j < 8; ++j) {
            s[j] = fmaf(s[j], lam, b2f(vv.e[j]));
            o.e[j] = __float2bfloat16(b2f(qq.e[j]) * s[j]);
        }
        *(bf8*)(&lds_ret[t][f0]) = o;
    }
    __syncthreads();

    // ---- phase 2: per-row LN + SiLU gate. wave w does rows w, w+2, ... ----
    const int lane = tid & 63;
    const int wv   = tid >> 6;

    // cache gamma/beta for this lane's two feature groups (lane*8, 512+lane*8)
    float gmA[8], btA[8], gmB[8], btB[8];
#pragma unroll
    for (int j = 0; j < 8; j += 4) {
        *(float4*)(gmA + j) = *(const float4*)(gamma  + lane * 8 + j);
        *(float4*)(btA + j) = *(const float4*)(betaln + lane * 8 + j);
        *(float4*)(gmB + j) = *(const float4*)(gamma  + 512 + lane * 8 + j);
        *(float4*)(btB + j) = *(const float4*)(betaln + 512 + lane * 8 + j);
    }

    for (int t = wv; t < SCC; t += 2) {
        bf8 rA = *(const bf8*)(&lds_ret[t][lane * 8]);
        bf8 rB = *(const bf8*)(&lds_ret[t][512 + lane * 8]);

        float xa[8], xb2[8];
        float sum = 0.f, sq = 0.f;
#pragma unroll
        for (int j = 0; j < 8; ++j) {
            xa[j]  = b2f(rA.e[j]);
            xb2[j] = b2f(rB.e[j]);
            sum += xa[j] + xb2[j];
            sq  += xa[j] * xa[j] + xb2[j] * xb2[j];
        }
#pragma unroll
        for (int off = 32; off >= 1; off >>= 1) {
            sum += __shfl_xor(sum, off, 64);
            sq  += __shfl_xor(sq,  off, 64);
        }
        const float mu   = sum * (1.0f / DD);
        const float var  = sq * (1.0f / DD) - mu * mu;
        const float rstd = rsqrtf(var + LN_EPS);

        const size_t row = (size_t)(b * LL + c * SCC + t);
        const bf16* gp = qvg + row * LDQVG + 2048 + lane * 8;
        bf8 gA = *(const bf8*)(gp);
        bf8 gB = *(const bf8*)(gp + 512);

        bf8 oA, oB;
#pragma unroll
        for (int j = 0; j < 8; ++j) {
            float ya = (xa[j]  - mu) * rstd * gmA[j] + btA[j];
            float yb = (xb2[j] - mu) * rstd * gmB[j] + btB[j];
            float ga = b2f(gA.e[j]);
            float gb = b2f(gB.e[j]);
            oA.e[j] = __float2bfloat16(ya * (ga / (1.0f + expf(-ga))));
            oB.e[j] = __float2bfloat16(yb * (gb / (1.0f + expf(-gb))));
        }
        bf16* zp = z + row * DD + lane * 8;
        *(bf8*)(zp)       = oA;
        *(bf8*)(zp + 512) = oB;
    }
}

// ---------------------------------------------------------------------------
// launch
// ---------------------------------------------------------------------------
extern "C" void kernel_launch(void* const* d_in, const int* in_sizes, int n_in,
                              void* d_out, int out_size, void* d_ws, size_t ws_size,
                              hipStream_t stream) {
    const float* x     = (const float*)d_in[0];
    const float* Wq    = (const float*)d_in[1];
    const float* Wv    = (const float*)d_in[2];
    const float* Wo    = (const float*)d_in[3];
    const float* Wg    = (const float*)d_in[4];
    const float* beta  = (const float*)d_in[5];
    const float* ln_g  = (const float*)d_in[6];
    const float* ln_b  = (const float*)d_in[7];
    float* out = (float*)d_out;

    char* ws = (char*)d_ws;
    // workspace (136MB total, time-multiplexed):
    //   @0    : xb 32MB (cvt -> QVG GEMM)  ->  S 4MB (chunksum -> carry)
    //           -> zb 32MB (apply_ln -> final GEMM)
    //   @32MB : wqb 6MB (wq|wv|wg; dead after QVG GEMM) -> T 4MB (carry -> apply)
    //   @38MB : wob 2MB (live until final GEMM)
    //   @40MB : qvg 96MB [M,3072] = q|v|g per row
    bf16*  xb   = (bf16*)ws;
    float* Sbuf = (float*)ws;                                  // alias xb (dead)
    bf16*  wqb  = (bf16*)(ws + (size_t)32 * 1024 * 1024);
    float* Tbuf = (float*)(ws + (size_t)32 * 1024 * 1024);     // alias wqb (dead)
    bf16*  wob  = wqb + 3 * 1048576;
    bf16*  qvg  = (bf16*)(ws + (size_t)40 * 1024 * 1024);
    bf16*  zb   = xb;

    // all dtype conversions in one dispatch (x + 4 weights)
    cvt_all<<<dim3(16384 + 4096), dim3(256), 0, stream>>>(x, Wq, Wv, Wg, Wo, xb, wqb);

    // fused QVG GEMM: [M,1024] x [3072,1024]^T -> [M,3072]
    gemm_bt<bf16, DD><<<dim3(MM / 128, LDQVG / 128), dim3(256), 0, stream>>>(
        xb, wqb, qvg, MM, LDQVG, LDQVG);

    // exact two-phase retention scan + fused LN/gate
    scan_chunksum<<<dim3(NCHUNK, 2, BB), dim3(64), 0, stream>>>(qvg, beta, Sbuf);
    scan_carry<<<dim3(64), dim3(64), 0, stream>>>(Sbuf, Tbuf, beta);
    scan_apply_ln<<<dim3(NCHUNK, BB), dim3(128), 0, stream>>>(
        qvg, beta, Tbuf, ln_g, ln_b, zb);

    gemm_bt<float, DD><<<dim3(MM / 128, DD / 128), dim3(256), 0, stream>>>(
        zb, wob, out, MM, DD, DD);
}